// Round 3
// 1302.050 us; speedup vs baseline: 1.3565x; 1.3565x over previous
//
#include <hip/hip_runtime.h>

// RNN_73701638799445: 2-layer tanh RNN.
// v2r2 (third submit; two prior "container failed" results believed to be infra —
// source triple-audited: no divergent barriers, all indices bounds-checked
// numerically, swizzles proven bijective for both GEMM shapes):
//     (a) deduplicated split-bf16 layouts (B0c=[Whi|Wlo], B1c=[W1hi Wh1hi|W1lo Wh1lo],
//         states compacted the same way) -> 96MB/phase instead of 144MB, same math;
//     (b) phase blocks pinned n-slice<->XCD (lbid&7) so weight slices stay L2-resident
//         across the 65 phase launches (per-XCD working set ~3MB < 4MB L2);
//     (c) XCD n-band swizzle in gemm_bt_bias (VPAD->10240 so gridDim.x%8==0) for
//         decoder L2 locality (Wd band 2.6MB/XCD reused across all m-tiles).

#define S_LEN 64
#define BATCH 64
#define HID   1024
#define VOCAB 10000
#define VPAD  10240           // 80 * 128
#define SB    4096            // S_LEN * BATCH
#define SBV   40960000        // SB * VOCAB

typedef __attribute__((ext_vector_type(4))) float  f32x4;
typedef __attribute__((ext_vector_type(8))) __bf16 bf16x8;

__device__ inline unsigned short f2bf(float x) {
  union { float f; unsigned int u; } v; v.f = x;
  unsigned int r = v.u + 0x7fffu + ((v.u >> 16) & 1u);   // RNE
  return (unsigned short)(r >> 16);
}
__device__ inline float bf2f(unsigned short s) {
  union { unsigned int u; float f; } v; v.u = ((unsigned int)s) << 16;
  return v.f;
}

// ---------------- prep kernels ----------------

// x[s,b,:] = emb[inputs[s,b]] -> bf16, 4 elems/thread
__global__ __launch_bounds__(256) void prep_x(
    const int* __restrict__ inputs, const float* __restrict__ emb,
    unsigned short* __restrict__ Xbf) {
  int i = blockIdx.x * 256 + threadIdx.x;       // SB*HID/4 threads
  int row = i >> 8;                             // /256  (1024/4 chunks per row)
  int c4  = (i & 255) * 4;
  int tok = inputs[row];
  const float4 v = *reinterpret_cast<const float4*>(emb + (size_t)tok * HID + c4);
  unsigned short* o = Xbf + (size_t)row * HID + c4;
  o[0] = f2bf(v.x); o[1] = f2bf(v.y); o[2] = f2bf(v.z); o[3] = f2bf(v.w);
}

// W0 -> bf16; Wh0 -> B0c [Whi | Wlo] (row=2048); W1,Wh1 -> B1c [W1hi Wh1hi | W1lo Wh1lo] (row=4096)
__global__ __launch_bounds__(256) void prep_w(
    const float* __restrict__ W0, const float* __restrict__ Wh0,
    const float* __restrict__ W1, const float* __restrict__ Wh1,
    unsigned short* __restrict__ W0bf, unsigned short* __restrict__ B0c,
    unsigned short* __restrict__ B1c) {
  int id = blockIdx.x * 256 + threadIdx.x;      // HID*HID threads
  int n = id >> 10, k = id & 1023;
  W0bf[id] = f2bf(W0[id]);
  {
    float w = Wh0[id];
    unsigned short hi = f2bf(w);
    unsigned short lo = f2bf(w - bf2f(hi));
    size_t base = (size_t)n * 2048 + k;
    B0c[base] = hi; B0c[base + 1024] = lo;
  }
  {
    float w1 = W1[id], wh1 = Wh1[id];
    unsigned short h1i = f2bf(w1),  l1 = f2bf(w1 - bf2f(h1i));
    unsigned short hh  = f2bf(wh1), lh = f2bf(wh1 - bf2f(hh));
    size_t base = (size_t)n * 4096 + k;
    B1c[base]        = h1i; B1c[base + 1024] = hh;
    B1c[base + 2048] = l1;  B1c[base + 3072] = lh;
  }
}

// Wd -> bf16 padded to VPAD rows (pad rows = 0); bd -> padded f32
__global__ __launch_bounds__(256) void prep_wd(
    const float* __restrict__ Wd, const float* __restrict__ bd,
    unsigned short* __restrict__ Wdbf, float* __restrict__ bdp) {
  int id = blockIdx.x * 256 + threadIdx.x;      // VPAD*1024 threads
  int row = id >> 10;
  Wdbf[id] = (row < VOCAB) ? f2bf(Wd[id]) : (unsigned short)0;
  if (id < VPAD) bdp[id] = (id < VOCAB) ? bd[id] : 0.0f;
}

// init recurrent state buffers from `hidden` [2,B,H]
// A0 row (2048): [h0hi | h0lo];  A1 row (4096): [h0hi | h1hi | h0lo | h1lo]
__global__ __launch_bounds__(256) void prep_h(
    const float* __restrict__ hidden,
    unsigned short* __restrict__ A0b0,
    unsigned short* __restrict__ A1b0, unsigned short* __restrict__ A1b1) {
  int id = blockIdx.x * 256 + threadIdx.x;      // BATCH*HID threads
  int b = id >> 10, n = id & 1023;
  float h0 = hidden[id];
  float h1 = hidden[BATCH * HID + id];
  unsigned short h0hi = f2bf(h0), h0lo = f2bf(h0 - bf2f(h0hi));
  unsigned short h1hi = f2bf(h1), h1lo = f2bf(h1 - bf2f(h1hi));
  size_t a0 = (size_t)b * 2048 + n;
  A0b0[a0] = h0hi; A0b0[a0 + 1024] = h0lo;
  size_t a1 = (size_t)b * 4096 + n;
  A1b0[a1 + 1024] = h1hi; A1b0[a1 + 3072] = h1lo;
  A1b1[a1 + 1024] = h1hi; A1b1[a1 + 3072] = h1lo;
}

// ---------------- big bf16 GEMM (A row-major [M,K], B row-major [Npad,K], C=f32) ----------------
// C[m,n] = sum_k A[m,k]*B[n,k] + bias[n].  128x128 tile, BK=64, 4 waves (2x2 of 64x64).
// XCD n-band swizzle: each XCD owns gridDim.x/8 consecutive n-tiles across all m
// (B band ~2.6MB stays L2-resident; requires gridDim.x % 8 == 0, else identity).
__global__ __launch_bounds__(256) void gemm_bt_bias(
    const unsigned short* __restrict__ A, const unsigned short* __restrict__ B,
    const float* __restrict__ bias, float* __restrict__ C,
    int K, int N, int ldc) {
  unsigned bx = blockIdx.x, by = blockIdx.y;
  if ((gridDim.x & 7u) == 0u) {
    const unsigned lin = blockIdx.x + gridDim.x * blockIdx.y;
    const unsigned xpx = gridDim.x >> 3;        // n-tiles per XCD
    const unsigned xcd = lin & 7u;
    const unsigned idx = lin >> 3;
    bx = xcd * xpx + idx % xpx;
    by = idx / xpx;
  }
  const int m0 = by * 128;
  const int n0 = bx * 128;
  __shared__ __align__(16) unsigned short As[128 * 64];
  __shared__ __align__(16) unsigned short Bs[128 * 64];
  const int tid = threadIdx.x;
  const int lane = tid & 63, w = tid >> 6;
  const int wm = w >> 1, wn = w & 1;
  f32x4 acc[4][4] = {};
  for (int k0 = 0; k0 < K; k0 += 64) {
#pragma unroll
    for (int i = 0; i < 4; ++i) {
      int off = i * 256 + tid;          // 16B chunk id
      int row = off >> 3;
      int c8  = off & 7;
      __builtin_amdgcn_global_load_lds(
          (const __attribute__((address_space(1))) unsigned int*)(const void*)
              (A + (size_t)(m0 + row) * K + k0 + c8 * 8),
          (__attribute__((address_space(3))) unsigned int*)(void*)(As + (size_t)off * 8),
          16, 0, 0);
      __builtin_amdgcn_global_load_lds(
          (const __attribute__((address_space(1))) unsigned int*)(const void*)
              (B + (size_t)(n0 + row) * K + k0 + c8 * 8),
          (__attribute__((address_space(3))) unsigned int*)(void*)(Bs + (size_t)off * 8),
          16, 0, 0);
    }
    __syncthreads();
#pragma unroll
    for (int kk = 0; kk < 64; kk += 32) {
      bf16x8 af[4], bfr[4];
#pragma unroll
      for (int f = 0; f < 4; ++f) {
        int ar = wm * 64 + f * 16 + (lane & 15);
        int ac = kk + (lane >> 4) * 8;
        af[f]  = *reinterpret_cast<const bf16x8*>(&As[ar * 64 + ac]);
        int br = wn * 64 + f * 16 + (lane & 15);
        bfr[f] = *reinterpret_cast<const bf16x8*>(&Bs[br * 64 + ac]);
      }
#pragma unroll
      for (int i = 0; i < 4; ++i)
#pragma unroll
        for (int j = 0; j < 4; ++j)
          acc[i][j] = __builtin_amdgcn_mfma_f32_16x16x32_bf16(af[i], bfr[j], acc[i][j], 0, 0, 0);
    }
    __syncthreads();
  }
  const int rbase = (lane >> 4) * 4;
  const int cbase = lane & 15;
#pragma unroll
  for (int i = 0; i < 4; ++i) {
#pragma unroll
    for (int j = 0; j < 4; ++j) {
      int col = n0 + wn * 64 + j * 16 + cbase;
      if (col < N) {
        float bv = bias[col];
#pragma unroll
        for (int r = 0; r < 4; ++r) {
          int row = m0 + wm * 64 + i * 16 + rbase + r;
          C[(size_t)row * ldc + col] = acc[i][j][r] + bv;
        }
      }
    }
  }
}

// ---------------- recurrence phase kernel ----------------
// blocks [0,256): layer0 step t  : h0_t  = tanh(U0[t] + h0_{t-1} @ Wh0^T)      (split-bf16)
// blocks [256,512): layer1 step t-1: h1_{t-1} = tanh(h0_{t-1}@W1^T + h1_{t-2}@Wh1^T + b1)
// Deduplicated layouts; per k-chunk: acc += a_hi*b_hi + a_hi*b_lo + a_lo*b_hi.
// n-slice pinned to XCD via (lbid & 7) so each XCD's weight slice stays in its L2.
__global__ __launch_bounds__(256) void phase_kernel(
    const unsigned short* __restrict__ A0,  unsigned short* __restrict__ A0n,
    const unsigned short* __restrict__ B0,  const float* __restrict__ U0t,
    const unsigned short* __restrict__ A1,  unsigned short* __restrict__ A1n,
    const unsigned short* __restrict__ B1,  const float* __restrict__ b1,
    unsigned short* __restrict__ H1t,
    float* __restrict__ h0f32, float* __restrict__ h1f32,
    int do0, int do1) {
  const int bid = blockIdx.x;
  const int layer = bid >> 8;
  if (layer == 0 && !do0) return;
  if (layer == 1 && !do1) return;
  const int lbid = bid & 255;
  const int xcd = lbid & 7;                  // XCD pin: round-robin dispatch
  const int sub = lbid >> 3;                 // 0..31
  const int m0 = (sub >> 3) << 4;            // 0,16,32,48
  const int n0 = xcd * 128 + ((sub & 7) << 4);
  const int tid = threadIdx.x, lane = tid & 63, w = tid >> 6;
  const int seg = layer ? 2048 : 1024;       // unique hi-segment length
  const int Ks  = seg >> 2;                  // per-wave k-slice of the segment
  const int ld  = seg * 2;                   // row stride (elements) of A and B
  const unsigned short* Ap = layer ? A1 : A0;
  const unsigned short* Bp = layer ? B1 : B0;
  const int kbeg = w * Ks;
  const int arow = m0 + (lane & 15);
  const int brow = n0 + (lane & 15);
  const int koff = (lane >> 4) * 8;
  const unsigned short* aP = Ap + (size_t)arow * ld + kbeg + koff;
  const unsigned short* bP = Bp + (size_t)brow * ld + kbeg + koff;
  f32x4 acc = {0.f, 0.f, 0.f, 0.f};
#pragma unroll 4
  for (int kc = 0; kc < Ks; kc += 32) {
    bf16x8 ah = *reinterpret_cast<const bf16x8*>(aP + kc);
    bf16x8 al = *reinterpret_cast<const bf16x8*>(aP + seg + kc);
    bf16x8 bh = *reinterpret_cast<const bf16x8*>(bP + kc);
    bf16x8 bl = *reinterpret_cast<const bf16x8*>(bP + seg + kc);
    acc = __builtin_amdgcn_mfma_f32_16x16x32_bf16(ah, bh, acc, 0, 0, 0);
    acc = __builtin_amdgcn_mfma_f32_16x16x32_bf16(ah, bl, acc, 0, 0, 0);
    acc = __builtin_amdgcn_mfma_f32_16x16x32_bf16(al, bh, acc, 0, 0, 0);
  }
  __shared__ float red[4][256];
  const int rrow = (lane >> 4) * 4;
  const int ccol = lane & 15;
#pragma unroll
  for (int r = 0; r < 4; ++r) red[w][(rrow + r) * 16 + ccol] = acc[r];
  __syncthreads();
  {
    float v = red[0][tid] + red[1][tid] + red[2][tid] + red[3][tid];
    int b   = m0 + (tid >> 4);
    int col = n0 + (tid & 15);
    if (layer == 0) {
      float h = tanhf(v + U0t[(size_t)b * HID + col]);
      unsigned short hi = f2bf(h);
      unsigned short lo = f2bf(h - bf2f(hi));
      size_t a0 = (size_t)b * 2048 + col;
      A0n[a0] = hi; A0n[a0 + 1024] = lo;
      size_t a1 = (size_t)b * 4096 + col;
      A1n[a1] = hi; A1n[a1 + 2048] = lo;
      h0f32[(size_t)b * HID + col] = h;
    } else {
      float h = tanhf(v + b1[col]);
      unsigned short hi = f2bf(h);
      unsigned short lo = f2bf(h - bf2f(hi));
      size_t a1 = (size_t)b * 4096 + col;
      A1n[a1 + 1024] = hi; A1n[a1 + 3072] = lo;
      H1t[(size_t)b * HID + col] = hi;
      h1f32[(size_t)b * HID + col] = h;
    }
  }
}

// ---------------- launcher ----------------

extern "C" void kernel_launch(void* const* d_in, const int* in_sizes, int n_in,
                              void* d_out, int out_size, void* d_ws, size_t ws_size,
                              hipStream_t stream) {
  (void)in_sizes; (void)n_in; (void)out_size; (void)ws_size;
  const int*   inputs = (const int*)  d_in[0];
  const float* hidden = (const float*)d_in[1];
  const float* emb    = (const float*)d_in[2];
  const float* W0     = (const float*)d_in[3];
  const float* Wh0    = (const float*)d_in[4];
  const float* b0     = (const float*)d_in[5];
  const float* W1     = (const float*)d_in[6];
  const float* Wh1    = (const float*)d_in[7];
  const float* b1     = (const float*)d_in[8];
  const float* Wd     = (const float*)d_in[9];
  const float* bd     = (const float*)d_in[10];

  // scratch inside d_out (consumed before the decoder overwrites logits)
  float*          U0  = (float*)d_out;                                       // 16MB
  unsigned short* Xbf = (unsigned short*)((char*)d_out + (size_t)16777216);  // 8MB

  // persistent scratch in d_ws
  char* ws = (char*)d_ws;
  size_t off = 0;
  auto alloc = [&](size_t bytes) { size_t p = off; off = (off + bytes + 255) & ~(size_t)255; return p; };
  unsigned short* W0bf = (unsigned short*)(ws + alloc((size_t)HID * HID * 2));
  unsigned short* Wdbf = (unsigned short*)(ws + alloc((size_t)VPAD * HID * 2));
  float*          bdp  = (float*)         (ws + alloc((size_t)VPAD * 4));
  unsigned short* B0c  = (unsigned short*)(ws + alloc((size_t)HID * 2048 * 2));
  unsigned short* B1c  = (unsigned short*)(ws + alloc((size_t)HID * 4096 * 2));
  unsigned short* H1bf = (unsigned short*)(ws + alloc((size_t)SB * HID * 2));
  unsigned short* A0b[2], *A1b[2];
  A0b[0] = (unsigned short*)(ws + alloc((size_t)BATCH * 2048 * 2));
  A0b[1] = (unsigned short*)(ws + alloc((size_t)BATCH * 2048 * 2));
  A1b[0] = (unsigned short*)(ws + alloc((size_t)BATCH * 4096 * 2));
  A1b[1] = (unsigned short*)(ws + alloc((size_t)BATCH * 4096 * 2));

  float* hid0 = (float*)d_out + (size_t)SBV;            // final h0 [B,H]
  float* hid1 = hid0 + (size_t)BATCH * HID;             // final h1 [B,H]

  // prep
  prep_x <<<SB * HID / 4 / 256, 256, 0, stream>>>(inputs, emb, Xbf);
  prep_w <<<HID * HID / 256,    256, 0, stream>>>(W0, Wh0, W1, Wh1, W0bf, B0c, B1c);
  prep_wd<<<VPAD * HID / 256,   256, 0, stream>>>(Wd, bd, Wdbf, bdp);
  prep_h <<<BATCH * HID / 256,  256, 0, stream>>>(hidden, A0b[0], A1b[0], A1b[1]);

  // U0 = X @ W0^T + b0
  gemm_bt_bias<<<dim3(HID / 128, SB / 128), 256, 0, stream>>>(
      Xbf, W0bf, b0, U0, HID, HID, HID);

  // 65 phases: phase t = layer0(t) + layer1(t-1)
  for (int t = 0; t <= S_LEN; ++t) {
    const float* U0t = U0 + (size_t)(t < S_LEN ? t : 0) * BATCH * HID;
    unsigned short* H1t = H1bf + (size_t)(t > 0 ? (t - 1) : 0) * BATCH * HID;
    phase_kernel<<<512, 256, 0, stream>>>(
        A0b[t & 1], A0b[(t + 1) & 1], B0c, U0t,
        A1b[t & 1], A1b[(t + 1) & 1], B1c, b1,
        H1t, hid0, hid1,
        (t < S_LEN) ? 1 : 0, (t > 0) ? 1 : 0);
  }

  // logits = H1 @ Wd^T + bd
  gemm_bt_bias<<<dim3(VPAD / 128, SB / 128), 256, 0, stream>>>(
      H1bf, Wdbf, bdp, (float*)d_out, HID, VOCAB, VOCAB);
}